// Round 12
// baseline (992.233 us; speedup 1.0000x reference)
//
#include <hip/hip_runtime.h>
#include <math.h>

// Problem constants (fixed by the reference: B=256, N=1024, S=16, 21 iters)
static constexpr int S_ = 16;
static constexpr int N_ = 1024;
static constexpr int B_ = 256;
static constexpr int ITERS = 21;
#define EPSC 1e-10f

using short8 = __attribute__((ext_vector_type(8))) short;
using f32x4  = __attribute__((ext_vector_type(4))) float;

// ---------------- bf16 helpers (raw ushort bits) ----------------
__device__ __forceinline__ float bf2f(unsigned short h) {
    union { unsigned int u; float f; } v; v.u = ((unsigned int)h) << 16; return v.f;
}
__device__ __forceinline__ unsigned short f2bf(float f) {
    union { float f; unsigned int u; } v; v.f = f;
    unsigned int r = v.u + 0x7fffu + ((v.u >> 16) & 1u);   // round-nearest-even
    return (unsigned short)(r >> 16);
}
__device__ __forceinline__ unsigned int pack2(float a, float b) {
    return (unsigned int)f2bf(a) | ((unsigned int)f2bf(b) << 16);
}

// la0 = log_alpha + gumbel_noise(u), noise = -log(EPS - log(u + EPS)).
__device__ __forceinline__ float la0_of(float uv, float lav) {
    float t1 = __logf(uv + EPSC);
    float t2 = EPSC - t1;
    return lav - __logf(t2);
}

__device__ __forceinline__ void unpack16(const uint4& a, const uint4& b, float* kf) {
    kf[0]  = bf2f((unsigned short)(a.x & 0xffffu)); kf[1]  = bf2f((unsigned short)(a.x >> 16));
    kf[2]  = bf2f((unsigned short)(a.y & 0xffffu)); kf[3]  = bf2f((unsigned short)(a.y >> 16));
    kf[4]  = bf2f((unsigned short)(a.z & 0xffffu)); kf[5]  = bf2f((unsigned short)(a.z >> 16));
    kf[6]  = bf2f((unsigned short)(a.w & 0xffffu)); kf[7]  = bf2f((unsigned short)(a.w >> 16));
    kf[8]  = bf2f((unsigned short)(b.x & 0xffffu)); kf[9]  = bf2f((unsigned short)(b.x >> 16));
    kf[10] = bf2f((unsigned short)(b.y & 0xffffu)); kf[11] = bf2f((unsigned short)(b.y >> 16));
    kf[12] = bf2f((unsigned short)(b.z & 0xffffu)); kf[13] = bf2f((unsigned short)(b.z >> 16));
    kf[14] = bf2f((unsigned short)(b.w & 0xffffu)); kf[15] = bf2f((unsigned short)(b.w >> 16));
}

// ---------------------------------------------------------------------------
// Last-block ticket (G16 pattern: device-scope atomics, no spin, no dispatch-
// order assumption, deadlock-free). __syncthreads drains every wave's stores
// to L2 (compiler emits s_waitcnt vmcnt(0) before s_barrier); the ACQ_REL
// agent atomic's release half writes L2 back to IF, its acquire half (on the
// winner) invalidates stale lines so plain loads after the second barrier see
// every block's partial. Winner identity varies; its computation (fixed slab
// order) is bitwise deterministic.
// ---------------------------------------------------------------------------
__device__ __forceinline__ bool ticket_last(unsigned int* cnt, unsigned int expected) {
    __shared__ int lastf;
    __syncthreads();
    if (threadIdx.x == 0) {
        unsigned int old = __hip_atomic_fetch_add(cnt, 1u, __ATOMIC_ACQ_REL,
                                                  __HIP_MEMORY_SCOPE_AGENT);
        lastf = (old == expected - 1u);
    }
    __syncthreads();
    return lastf != 0;
}

// Finisher: V[j] = 1/sum_{q<NS} partial[q][j], slab order ascending (bitwise
// identical to the old reduce_V). 256 threads x 4 contiguous cols each.
template<int NS>
__device__ __forceinline__ void finish_V(const float* __restrict__ pbase,
                                         float* __restrict__ Vp) {
    const int t = threadIdx.x;
    const float* p = pbase + t * 4;
    float4 acc = make_float4(0.f, 0.f, 0.f, 0.f);
    #pragma unroll
    for (int q = 0; q < NS; ++q) {
        float4 v = *(const float4*)(p + (size_t)q * N_);
        acc.x += v.x; acc.y += v.y; acc.z += v.z; acc.w += v.w;
    }
    float4 o = make_float4(1.f / acc.x, 1.f / acc.y, 1.f / acc.z, 1.f / acc.w);
    *(float4*)(Vp + t * 4) = o;
}

// ===========================================================================
// build_K2 (2048 blocks): K bf16 + colsum seed (U=1) + last-block V0 reduce.
// 16 samples x 128 slabs x 8 rows; 2 rows/wave.
// ===========================================================================
__global__ void __launch_bounds__(256)
build_K2(const float* __restrict__ u, const float* __restrict__ la,
         unsigned short* __restrict__ Kb, float* __restrict__ partial,
         float* __restrict__ V, unsigned int* __restrict__ cnt) {
    const int bid = blockIdx.x;
    const int s    = (bid & 7) + 8 * ((bid >> 3) & 1);
    const int slab = bid >> 4;                 // 0..127
    const int t = threadIdx.x, wv = t >> 6, l = t & 63;
    const int i0 = slab * 8 + wv * 2;

    float cs[16];
    #pragma unroll
    for (int e = 0; e < 16; ++e) cs[e] = 0.f;

    f32x4 uu[2][4];
    float4 ll[2][4];
    #pragma unroll
    for (int rr = 0; rr < 2; ++rr) {
        const int i = i0 + rr;
        const float* up  = u  + ((size_t)s * N_ + i) * N_ + 8 * l;
        const float* lap = la + (size_t)i * N_ + 8 * l;
        uu[rr][0] = __builtin_nontemporal_load((const f32x4*)(up));
        uu[rr][1] = __builtin_nontemporal_load((const f32x4*)(up + 4));
        uu[rr][2] = __builtin_nontemporal_load((const f32x4*)(up + 512));
        uu[rr][3] = __builtin_nontemporal_load((const f32x4*)(up + 516));
        ll[rr][0] = *(const float4*)(lap);
        ll[rr][1] = *(const float4*)(lap + 4);
        ll[rr][2] = *(const float4*)(lap + 512);
        ll[rr][3] = *(const float4*)(lap + 516);
    }
    #pragma unroll
    for (int rr = 0; rr < 2; ++rr) {
        const int i = i0 + rr;
        #pragma unroll
        for (int h = 0; h < 2; ++h) {
            const float uf[8] = {uu[rr][2*h][0], uu[rr][2*h][1], uu[rr][2*h][2], uu[rr][2*h][3],
                                 uu[rr][2*h+1][0], uu[rr][2*h+1][1], uu[rr][2*h+1][2], uu[rr][2*h+1][3]};
            const float lf[8] = {ll[rr][2*h].x, ll[rr][2*h].y, ll[rr][2*h].z, ll[rr][2*h].w,
                                 ll[rr][2*h+1].x, ll[rr][2*h+1].y, ll[rr][2*h+1].z, ll[rr][2*h+1].w};
            unsigned int pk[4];
            #pragma unroll
            for (int e = 0; e < 4; ++e) {
                float k0 = __expf(lf[2*e])   / (EPSC - __logf(uf[2*e]   + EPSC));
                float k1 = __expf(lf[2*e+1]) / (EPSC - __logf(uf[2*e+1] + EPSC));
                unsigned short b0 = f2bf(k0), b1 = f2bf(k1);
                pk[e] = (unsigned int)b0 | ((unsigned int)b1 << 16);
                cs[h*8 + 2*e]     += bf2f(b0);
                cs[h*8 + 2*e + 1] += bf2f(b1);
            }
            *(uint4*)(Kb + ((size_t)s * N_ + i) * N_ + h * 512 + 8 * l) =
                make_uint4(pk[0], pk[1], pk[2], pk[3]);
        }
    }

    // combine 4 waves' colsums -> partial[s][slab][:]
    __shared__ float lds[4][1024];
    *(float4*)&lds[wv][8*l]           = make_float4(cs[0], cs[1], cs[2], cs[3]);
    *(float4*)&lds[wv][8*l + 4]       = make_float4(cs[4], cs[5], cs[6], cs[7]);
    *(float4*)&lds[wv][512 + 8*l]     = make_float4(cs[8], cs[9], cs[10], cs[11]);
    *(float4*)&lds[wv][512 + 8*l + 4] = make_float4(cs[12], cs[13], cs[14], cs[15]);
    __syncthreads();
    const int j = t * 4;
    float4 p0 = *(const float4*)&lds[0][j];
    float4 p1 = *(const float4*)&lds[1][j];
    float4 p2 = *(const float4*)&lds[2][j];
    float4 p3 = *(const float4*)&lds[3][j];
    float4 o;
    o.x = p0.x + p1.x + p2.x + p3.x;  o.y = p0.y + p1.y + p2.y + p3.y;
    o.z = p0.z + p1.z + p2.z + p3.z;  o.w = p0.w + p1.w + p2.w + p3.w;
    float* pbase = partial + (size_t)s * 128 * N_;
    *(float4*)(pbase + (size_t)slab * N_ + j) = o;

    // last block of this sample reduces 128 slabs -> V0
    if (ticket_last(cnt + s, 128))
        finish_V<128>(pbase, V + s * N_);
}

// ===========================================================================
// sink_iter: fused row pass + next col-pass partials + last-block V reduce.
// 1024 blocks, 16 rows/block, 4 rows/wave.
//   U_i = 1 / sum_j K[i][j] V_j ;  partial[s][slab][j] = sum_i K[i][j] U_i
//   last block per sample: V_next[j] = 1 / sum_slab partial[s][slab][j]
// ===========================================================================
__global__ void __launch_bounds__(256)
sink_iter(const unsigned short* __restrict__ Kb, const float* __restrict__ V,
          float* __restrict__ U, float* __restrict__ partial,
          float* __restrict__ Vnext, unsigned int* __restrict__ cnt,
          int do_colsum) {
    const int bid = blockIdx.x;
    const int s    = (bid & 7) + 8 * ((bid >> 3) & 1);
    const int slab = bid >> 4;                 // 0..63
    const int t = threadIdx.x, wv = t >> 6, l = t & 63;

    // lane-owned columns: 8l..8l+7 and 512+8l..512+8l+7
    float v[16];
    const float* Vp = V + s * N_;
    *(float4*)&v[0]  = *(const float4*)(Vp + 8*l);
    *(float4*)&v[4]  = *(const float4*)(Vp + 8*l + 4);
    *(float4*)&v[8]  = *(const float4*)(Vp + 512 + 8*l);
    *(float4*)&v[12] = *(const float4*)(Vp + 512 + 8*l + 4);

    float cs[16];
    #pragma unroll
    for (int e = 0; e < 16; ++e) cs[e] = 0.f;

    const int i0 = slab * 16 + wv * 4;
    const unsigned short* rowp = Kb + ((size_t)s * N_ + i0) * N_;
    #pragma unroll
    for (int rr = 0; rr < 4; ++rr, rowp += N_) {
        uint4 ra = *(const uint4*)(rowp + 8*l);
        uint4 rb = *(const uint4*)(rowp + 512 + 8*l);
        float kf[16];
        unpack16(ra, rb, kf);
        float dot = 0.f;
        #pragma unroll
        for (int e = 0; e < 16; ++e) dot += kf[e] * v[e];
        #pragma unroll
        for (int m = 32; m >= 1; m >>= 1) dot += __shfl_xor(dot, m);
        const float ui = 1.0f / dot;
        if (l == 0) U[s * N_ + i0 + rr] = ui;
        #pragma unroll
        for (int e = 0; e < 16; ++e) cs[e] += kf[e] * ui;
    }

    if (!do_colsum) return;
    __shared__ float lds[4][1024];
    *(float4*)&lds[wv][8*l]           = make_float4(cs[0], cs[1], cs[2], cs[3]);
    *(float4*)&lds[wv][8*l + 4]       = make_float4(cs[4], cs[5], cs[6], cs[7]);
    *(float4*)&lds[wv][512 + 8*l]     = make_float4(cs[8], cs[9], cs[10], cs[11]);
    *(float4*)&lds[wv][512 + 8*l + 4] = make_float4(cs[12], cs[13], cs[14], cs[15]);
    __syncthreads();
    const int j = t * 4;
    float4 p0 = *(const float4*)&lds[0][j];
    float4 p1 = *(const float4*)&lds[1][j];
    float4 p2 = *(const float4*)&lds[2][j];
    float4 p3 = *(const float4*)&lds[3][j];
    float4 o;
    o.x = p0.x + p1.x + p2.x + p3.x;  o.y = p0.y + p1.y + p2.y + p3.y;
    o.z = p0.z + p1.z + p2.z + p3.z;  o.w = p0.w + p1.w + p2.w + p3.w;
    float* pbase = partial + (size_t)s * 64 * N_;
    *(float4*)(pbase + (size_t)slab * N_ + j) = o;

    // last block of this sample reduces 64 slabs -> V for the next launch
    if (ticket_last(cnt + s, 64))
        finish_V<64>(pbase, Vnext + s * N_);
}

// ===========================================================================
// transpose_K: KbT[s][m][k] = Kb[s][k][m]  (after the loop; the partial
// buffer aliases the front of KbT and is dead by then).
// ===========================================================================
__global__ void __launch_bounds__(256)
transpose_K(const unsigned short* __restrict__ Kb, unsigned short* __restrict__ KbT) {
    const int s = blockIdx.z, k0 = blockIdx.x * 64, m0 = blockIdx.y * 64;
    __shared__ unsigned short tile[64][66];
    const int t = threadIdx.x, c4 = (t & 15) * 4, rr = t >> 4;
    const unsigned short* src = Kb + (size_t)s * N_ * N_;
    unsigned short* dst = KbT + (size_t)s * N_ * N_;
    #pragma unroll
    for (int q = 0; q < 4; ++q) {
        const int r = q * 16 + rr;
        ushort4 v = *(const ushort4*)(src + (size_t)(k0 + r) * N_ + m0 + c4);
        tile[r][c4] = v.x; tile[r][c4 + 1] = v.y; tile[r][c4 + 2] = v.z; tile[r][c4 + 3] = v.w;
    }
    __syncthreads();
    #pragma unroll
    for (int q = 0; q < 4; ++q) {
        const int rm = q * 16 + rr;
        ushort4 v;
        v.x = tile[c4][rm]; v.y = tile[c4 + 1][rm];
        v.z = tile[c4 + 2][rm]; v.w = tile[c4 + 3][rm];
        *(ushort4*)(dst + (size_t)(m0 + rm) * N_ + k0 + c4) = v;
    }
}

// ===========================================================================
// mfma_out (512 threads, 8 waves, wave-tile 32x32): validated layouts.
// out[s][b][m] = V_m * sum_k (x[b][k]U_k) K[k][m], bf16 MFMA 16x16x32.
// BM=128 BN=64 BK=64, XOR-swizzled LDS, register prefetch.
// ===========================================================================
__global__ void __launch_bounds__(512)
mfma_out(const float* __restrict__ x, const unsigned short* __restrict__ KbT,
         const float* __restrict__ U, const float* __restrict__ V,
         float* __restrict__ out) {
    const int s  = blockIdx.z;
    const int m0 = blockIdx.x * 64;
    const int b0 = blockIdx.y * 128;
    const int t  = threadIdx.x;
    const int wid = t >> 6, l = t & 63;
    const int wr = wid & 3;      // b-quadrant: rows wr*32 .. +32
    const int wc = wid >> 2;     // m-half:    cols wc*32 .. +32

    __shared__ alignas(16) unsigned short lsA[128 * 64];  // [b][k] swizzled
    __shared__ alignas(16) unsigned short lsB[64 * 64];   // [m][k] swizzled, U folded

    f32x4 acc[2][2];
    #pragma unroll
    for (int fi = 0; fi < 2; ++fi)
        #pragma unroll
        for (int fj = 0; fj < 2; ++fj)
            acc[fi][fj] = (f32x4){0.f, 0.f, 0.f, 0.f};

    const unsigned short* Bp = KbT + ((size_t)s * N_ + m0) * N_;
    const float* Up = U + s * N_;

    float4 xa[2], xb[2];
    uint4  kv;
    float4 ua, ub;

    auto load_tile = [&](int k0) {
        #pragma unroll
        for (int i = 0; i < 2; ++i) {
            const int Lb  = i * 8192 + t * 16;
            const int row = Lb >> 7;
            const int kb  = Lb & 127;
            const float* xp = x + (size_t)(b0 + row) * N_ + k0 + (kb >> 1);
            xa[i] = *(const float4*)xp;
            xb[i] = *(const float4*)(xp + 4);
        }
        {
            const int Lb  = t * 16;
            const int row = Lb >> 7;
            const int kb  = Lb & 127;
            kv = *(const uint4*)((const char*)Bp + (size_t)row * 2048 + (k0 << 1) + kb);
            const int ke = k0 + (kb >> 1);
            ua = *(const float4*)(Up + ke);
            ub = *(const float4*)(Up + ke + 4);
        }
    };

    load_tile(0);
    for (int k0 = 0; k0 < N_; k0 += 64) {
        __syncthreads();
        #pragma unroll
        for (int i = 0; i < 2; ++i) {
            const int Lb  = i * 8192 + t * 16;
            const int row = Lb >> 7;
            const int kb  = Lb & 127;
            uint4 pk = make_uint4(pack2(xa[i].x, xa[i].y), pack2(xa[i].z, xa[i].w),
                                  pack2(xb[i].x, xb[i].y), pack2(xb[i].z, xb[i].w));
            *(uint4*)((char*)lsA + (row << 7) + (kb ^ ((row & 7) << 4))) = pk;
        }
        {
            const int Lb  = t * 16;
            const int row = Lb >> 7;
            const int kb  = Lb & 127;
            uint4 pk;
            pk.x = pack2(bf2f((unsigned short)(kv.x & 0xffffu)) * ua.x,
                         bf2f((unsigned short)(kv.x >> 16))     * ua.y);
            pk.y = pack2(bf2f((unsigned short)(kv.y & 0xffffu)) * ua.z,
                         bf2f((unsigned short)(kv.y >> 16))     * ua.w);
            pk.z = pack2(bf2f((unsigned short)(kv.z & 0xffffu)) * ub.x,
                         bf2f((unsigned short)(kv.z >> 16))     * ub.y);
            pk.w = pack2(bf2f((unsigned short)(kv.w & 0xffffu)) * ub.z,
                         bf2f((unsigned short)(kv.w >> 16))     * ub.w);
            *(uint4*)((char*)lsB + (row << 7) + (kb ^ ((row & 7) << 4))) = pk;
        }
        __syncthreads();
        if (k0 + 64 < N_) load_tile(k0 + 64);
        #pragma unroll
        for (int ks = 0; ks < 2; ++ks) {
            const int koff = ks * 64 + ((l >> 4) << 4);
            short8 afr[2], bfr[2];
            #pragma unroll
            for (int fi = 0; fi < 2; ++fi) {
                const int r = wr * 32 + fi * 16 + (l & 15);
                afr[fi] = *(const short8*)((const char*)lsA + (r << 7) + (koff ^ ((r & 7) << 4)));
            }
            #pragma unroll
            for (int fj = 0; fj < 2; ++fj) {
                const int r = wc * 32 + fj * 16 + (l & 15);
                bfr[fj] = *(const short8*)((const char*)lsB + (r << 7) + (koff ^ ((r & 7) << 4)));
            }
            #pragma unroll
            for (int fi = 0; fi < 2; ++fi)
                #pragma unroll
                for (int fj = 0; fj < 2; ++fj)
                    acc[fi][fj] = __builtin_amdgcn_mfma_f32_16x16x32_bf16(
                        afr[fi], bfr[fj], acc[fi][fj], 0, 0, 0);
        }
    }
    #pragma unroll
    for (int fj = 0; fj < 2; ++fj) {
        const int m = m0 + wc * 32 + fj * 16 + (l & 15);
        const float vm = V[s * N_ + m];
        #pragma unroll
        for (int fi = 0; fi < 2; ++fi) {
            const int b = b0 + wr * 32 + fi * 16 + ((l >> 4) << 2);
            float* op = out + ((size_t)s * B_ + b) * N_ + m;
            #pragma unroll
            for (int e = 0; e < 4; ++e)
                op[(size_t)e * N_] = acc[fi][fj][e] * vm;
        }
    }
}

// ===========================================================================
// FALLBACK PATH (round-1 proven kernels) — used only if ws is too small.
// ===========================================================================
__global__ void __launch_bounds__(256)
transpose_x(const float* __restrict__ x, float* __restrict__ xT) {
    __shared__ float tile[32][33];
    const int tx = threadIdx.x, ty = threadIdx.y;
    const int gx = blockIdx.x * 32, gy = blockIdx.y * 32;
    #pragma unroll
    for (int i = 0; i < 4; ++i)
        tile[ty + i * 8][tx] = x[(gy + ty + i * 8) * N_ + gx + tx];
    __syncthreads();
    #pragma unroll
    for (int i = 0; i < 4; ++i)
        xT[(size_t)(gx + ty + i * 8) * B_ + gy + tx] = tile[tx][ty + i * 8];
}

__global__ void __launch_bounds__(256)
col_pass(const float* __restrict__ u, const float* __restrict__ la,
         const float* __restrict__ r, float* __restrict__ c) {
    const int s = blockIdx.y, t = threadIdx.x;
    const int tx = t & 15, rg = t >> 4;
    const int j = blockIdx.x * 16 + tx;
    __shared__ alignas(16) float r_lds[N_];
    ((float4*)r_lds)[t] = ((const float4*)(r + s * N_))[t];
    __syncthreads();
    const float cj = c[s * N_ + j];
    const float* up = u + (size_t)s * N_ * N_;
    const int i0 = rg * 64;
    float acc = 0.f;
    #pragma unroll 4
    for (int ii = 0; ii < 64; ++ii) {
        const int i = i0 + ii;
        acc += __expf(la0_of(up[(size_t)i * N_ + j], la[i * N_ + j]) - r_lds[i] - cj);
    }
    __shared__ float sums[16][17];
    sums[rg][tx] = acc;
    __syncthreads();
    if (t < 16) {
        float tot = 0.f;
        #pragma unroll
        for (int k = 0; k < 16; ++k) tot += sums[k][t];
        c[s * N_ + blockIdx.x * 16 + t] = cj + __logf(tot);
    }
}

__global__ void __launch_bounds__(256)
row_pass(const float* __restrict__ u, const float* __restrict__ la,
         const float* __restrict__ c, float* __restrict__ r) {
    const int s = blockIdx.y, t = threadIdx.x;
    const int w = t >> 6, l = t & 63;
    const int i = blockIdx.x * 4 + w;
    __shared__ alignas(16) float c_lds[N_];
    ((float4*)c_lds)[t] = ((const float4*)(c + s * N_))[t];
    __syncthreads();
    const float ri = r[s * N_ + i];
    const float* up = u + (size_t)s * N_ * N_ + (size_t)i * N_;
    const float* lap = la + (size_t)i * N_;
    float acc = 0.f;
    #pragma unroll
    for (int k = 0; k < 16; ++k) {
        const int jj = l + (k << 6);
        acc += __expf(la0_of(up[jj], lap[jj]) - c_lds[jj] - ri);
    }
    #pragma unroll
    for (int m = 32; m >= 1; m >>= 1) acc += __shfl_xor(acc, m);
    if (l == 0) r[s * N_ + i] = ri + __logf(acc);
}

__global__ void __launch_bounds__(256)
matmul_out(const float* __restrict__ u, const float* __restrict__ la,
           const float* __restrict__ xT, const float* __restrict__ r,
           const float* __restrict__ c, float* __restrict__ out) {
    const int s = blockIdx.z, m0 = blockIdx.x * 64, b0 = blockIdx.y * 128;
    const int t = threadIdx.x, tx = t & 7, ty = t >> 3;
    __shared__ alignas(16) float Bs[16][64];
    float acc[4][8] = {};
    const float* up = u + (size_t)s * N_ * N_;
    const float* rp = r + s * N_;
    for (int k0 = 0; k0 < N_; k0 += 16) {
        __syncthreads();
        {
            const int kk = t >> 4, f4 = t & 15;
            const int k = k0 + kk;
            const float rk = rp[k];
            const float4 uv = *(const float4*)(up + (size_t)k * N_ + m0 + f4 * 4);
            const float4 lv = *(const float4*)(la + (size_t)k * N_ + m0 + f4 * 4);
            float4 p;
            p.x = __expf(la0_of(uv.x, lv.x) - rk);
            p.y = __expf(la0_of(uv.y, lv.y) - rk);
            p.z = __expf(la0_of(uv.z, lv.z) - rk);
            p.w = __expf(la0_of(uv.w, lv.w) - rk);
            *(float4*)(&Bs[kk][f4 * 4]) = p;
        }
        __syncthreads();
        #pragma unroll
        for (int kk = 0; kk < 16; ++kk) {
            const float4 a4 = *(const float4*)(xT + (size_t)(k0 + kk) * B_ + b0 + ty * 4);
            const float4 bA = *(const float4*)(&Bs[kk][tx * 8]);
            const float4 bB = *(const float4*)(&Bs[kk][tx * 8 + 4]);
            const float av[4] = {a4.x, a4.y, a4.z, a4.w};
            const float bv[8] = {bA.x, bA.y, bA.z, bA.w, bB.x, bB.y, bB.z, bB.w};
            #pragma unroll
            for (int rr = 0; rr < 4; ++rr)
                #pragma unroll
                for (int cc = 0; cc < 8; ++cc)
                    acc[rr][cc] += av[rr] * bv[cc];
        }
    }
    float cm[8];
    #pragma unroll
    for (int cc = 0; cc < 8; ++cc) cm[cc] = __expf(-c[s * N_ + m0 + tx * 8 + cc]);
    #pragma unroll
    for (int rr = 0; rr < 4; ++rr) {
        float4 o0, o1;
        o0.x = acc[rr][0] * cm[0]; o0.y = acc[rr][1] * cm[1];
        o0.z = acc[rr][2] * cm[2]; o0.w = acc[rr][3] * cm[3];
        o1.x = acc[rr][4] * cm[4]; o1.y = acc[rr][5] * cm[5];
        o1.z = acc[rr][6] * cm[6]; o1.w = acc[rr][7] * cm[7];
        float* op = out + ((size_t)s * B_ + b0 + ty * 4 + rr) * N_ + m0 + tx * 8;
        *(float4*)op       = o0;
        *(float4*)(op + 4) = o1;
    }
}

// ===========================================================================
extern "C" void kernel_launch(void* const* d_in, const int* in_sizes, int n_in,
                              void* d_out, int out_size, void* d_ws, size_t ws_size,
                              hipStream_t stream) {
    (void)in_sizes; (void)n_in; (void)out_size;
    const float* x  = (const float*)d_in[0];   // (256, 1024)
    const float* la = (const float*)d_in[1];   // (1024, 1024)
    const float* u  = (const float*)d_in[2];   // (16, 1024, 1024)
    float* out = (float*)d_out;                // (16, 256, 1024) f32

    const size_t KN = (size_t)S_ * N_ * N_;
    const size_t CNT_WORDS = (size_t)(1 + ITERS) * S_;   // per-launch ticket slots
    const size_t need = KN * 2 * 2               // Kb + KbT (bf16)
                      + (size_t)2 * S_ * N_ * 4  // U, V
                      + CNT_WORDS * 4;           // tickets

    if (ws_size >= need) {
        unsigned short* Kb  = (unsigned short*)d_ws;
        unsigned short* KbT = Kb + KN;
        float* partial = (float*)KbT;            // <=8MB alias, dead before transpose_K
        float* U = (float*)(KbT + KN);
        float* V = U + S_ * N_;
        unsigned int* cnt = (unsigned int*)(V + S_ * N_);

        // zero ticket counters every call (deterministic, graph-safe)
        (void)hipMemsetAsync(cnt, 0, CNT_WORDS * 4, stream);

        // 1) build K (bf16) + colsum seed; last block per sample reduces V0
        build_K2<<<2048, 256, 0, stream>>>(u, la, Kb, partial, V, cnt);

        // 2) 21 fused Sinkhorn iterations (one kernel each; V produced
        //    in-kernel by the last-finishing block per sample)
        for (int it = 0; it < ITERS; ++it) {
            sink_iter<<<1024, 256, 0, stream>>>(Kb, V, U, partial, V,
                                                cnt + (size_t)(1 + it) * S_,
                                                it == ITERS - 1 ? 0 : 1);
        }

        // 3) KbT for the matmul's B operand (partial is dead now)
        transpose_K<<<dim3(16, 16, 16), 256, 0, stream>>>(Kb, KbT);

        // 4) out = diag-scaled GEMM via bf16 MFMA (512-thread blocks)
        mfma_out<<<dim3(N_ / 64, B_ / 128, S_), 512, 0, stream>>>(x, KbT, U, V, out);
    } else {
        float* r  = (float*)d_ws;
        float* c  = r + S_ * N_;
        float* xT = c + S_ * N_;
        (void)hipMemsetAsync(d_ws, 0, 2 * S_ * N_ * sizeof(float), stream);
        transpose_x<<<dim3(N_ / 32, B_ / 32), dim3(32, 8), 0, stream>>>(x, xT);
        for (int it = 0; it < ITERS; ++it) {
            col_pass<<<dim3(N_ / 16, S_), 256, 0, stream>>>(u, la, r, c);
            row_pass<<<dim3(N_ / 4, S_),  256, 0, stream>>>(u, la, c, r);
        }
        matmul_out<<<dim3(N_ / 64, B_ / 128, S_), 256, 0, stream>>>(u, la, xT, r, c, out);
    }
}

// Round 13
// 304.912 us; speedup vs baseline: 3.2542x; 3.2542x over previous
//
#include <hip/hip_runtime.h>
#include <math.h>

// Problem constants (fixed by the reference: B=256, N=1024, S=16, 21 iters)
static constexpr int S_ = 16;
static constexpr int N_ = 1024;
static constexpr int B_ = 256;
static constexpr int ITERS = 21;
#define EPSC 1e-10f

using short8 = __attribute__((ext_vector_type(8))) short;
using f32x4  = __attribute__((ext_vector_type(4))) float;

// ---------------- bf16 helpers (raw ushort bits) ----------------
__device__ __forceinline__ float bf2f(unsigned short h) {
    union { unsigned int u; float f; } v; v.u = ((unsigned int)h) << 16; return v.f;
}
__device__ __forceinline__ unsigned short f2bf(float f) {
    union { float f; unsigned int u; } v; v.f = f;
    unsigned int r = v.u + 0x7fffu + ((v.u >> 16) & 1u);   // round-nearest-even
    return (unsigned short)(r >> 16);
}
__device__ __forceinline__ unsigned int pack2(float a, float b) {
    return (unsigned int)f2bf(a) | ((unsigned int)f2bf(b) << 16);
}

// la0 = log_alpha + gumbel_noise(u), noise = -log(EPS - log(u + EPS)).
__device__ __forceinline__ float la0_of(float uv, float lav) {
    float t1 = __logf(uv + EPSC);
    float t2 = EPSC - t1;
    return lav - __logf(t2);
}

__device__ __forceinline__ void unpack16(const uint4& a, const uint4& b, float* kf) {
    kf[0]  = bf2f((unsigned short)(a.x & 0xffffu)); kf[1]  = bf2f((unsigned short)(a.x >> 16));
    kf[2]  = bf2f((unsigned short)(a.y & 0xffffu)); kf[3]  = bf2f((unsigned short)(a.y >> 16));
    kf[4]  = bf2f((unsigned short)(a.z & 0xffffu)); kf[5]  = bf2f((unsigned short)(a.z >> 16));
    kf[6]  = bf2f((unsigned short)(a.w & 0xffffu)); kf[7]  = bf2f((unsigned short)(a.w >> 16));
    kf[8]  = bf2f((unsigned short)(b.x & 0xffffu)); kf[9]  = bf2f((unsigned short)(b.x >> 16));
    kf[10] = bf2f((unsigned short)(b.y & 0xffffu)); kf[11] = bf2f((unsigned short)(b.y >> 16));
    kf[12] = bf2f((unsigned short)(b.z & 0xffffu)); kf[13] = bf2f((unsigned short)(b.z >> 16));
    kf[14] = bf2f((unsigned short)(b.w & 0xffffu)); kf[15] = bf2f((unsigned short)(b.w >> 16));
}

// ===========================================================================
// build_K2 (2048 blocks; round-11-proven): K[s][i][j] bf16 + colsum seed
// (U=1): partial[s][slab][j] = sum_i K[i][j]. 16 samples x 128 slabs x 8 rows;
// 2 rows/wave, 16 float4 loads in flight. NO cross-block sync (r12 lesson:
// per-block agent-scope fences flush L2 and cost 5x the launch they save).
// ===========================================================================
__global__ void __launch_bounds__(256)
build_K2(const float* __restrict__ u, const float* __restrict__ la,
         unsigned short* __restrict__ Kb, float* __restrict__ partial) {
    const int bid = blockIdx.x;
    const int s    = (bid & 7) + 8 * ((bid >> 3) & 1);
    const int slab = bid >> 4;                 // 0..127
    const int t = threadIdx.x, wv = t >> 6, l = t & 63;
    const int i0 = slab * 8 + wv * 2;

    float cs[16];
    #pragma unroll
    for (int e = 0; e < 16; ++e) cs[e] = 0.f;

    f32x4 uu[2][4];
    float4 ll[2][4];
    #pragma unroll
    for (int rr = 0; rr < 2; ++rr) {
        const int i = i0 + rr;
        const float* up  = u  + ((size_t)s * N_ + i) * N_ + 8 * l;
        const float* lap = la + (size_t)i * N_ + 8 * l;
        uu[rr][0] = __builtin_nontemporal_load((const f32x4*)(up));
        uu[rr][1] = __builtin_nontemporal_load((const f32x4*)(up + 4));
        uu[rr][2] = __builtin_nontemporal_load((const f32x4*)(up + 512));
        uu[rr][3] = __builtin_nontemporal_load((const f32x4*)(up + 516));
        ll[rr][0] = *(const float4*)(lap);
        ll[rr][1] = *(const float4*)(lap + 4);
        ll[rr][2] = *(const float4*)(lap + 512);
        ll[rr][3] = *(const float4*)(lap + 516);
    }
    #pragma unroll
    for (int rr = 0; rr < 2; ++rr) {
        const int i = i0 + rr;
        #pragma unroll
        for (int h = 0; h < 2; ++h) {
            const float uf[8] = {uu[rr][2*h][0], uu[rr][2*h][1], uu[rr][2*h][2], uu[rr][2*h][3],
                                 uu[rr][2*h+1][0], uu[rr][2*h+1][1], uu[rr][2*h+1][2], uu[rr][2*h+1][3]};
            const float lf[8] = {ll[rr][2*h].x, ll[rr][2*h].y, ll[rr][2*h].z, ll[rr][2*h].w,
                                 ll[rr][2*h+1].x, ll[rr][2*h+1].y, ll[rr][2*h+1].z, ll[rr][2*h+1].w};
            unsigned int pk[4];
            #pragma unroll
            for (int e = 0; e < 4; ++e) {
                float k0 = __expf(lf[2*e])   / (EPSC - __logf(uf[2*e]   + EPSC));
                float k1 = __expf(lf[2*e+1]) / (EPSC - __logf(uf[2*e+1] + EPSC));
                unsigned short b0 = f2bf(k0), b1 = f2bf(k1);
                pk[e] = (unsigned int)b0 | ((unsigned int)b1 << 16);
                cs[h*8 + 2*e]     += bf2f(b0);
                cs[h*8 + 2*e + 1] += bf2f(b1);
            }
            *(uint4*)(Kb + ((size_t)s * N_ + i) * N_ + h * 512 + 8 * l) =
                make_uint4(pk[0], pk[1], pk[2], pk[3]);
        }
    }

    // combine 4 waves' colsums, write partial[s][slab][:] (128-slab layout)
    __shared__ float lds[4][1024];
    *(float4*)&lds[wv][8*l]           = make_float4(cs[0], cs[1], cs[2], cs[3]);
    *(float4*)&lds[wv][8*l + 4]       = make_float4(cs[4], cs[5], cs[6], cs[7]);
    *(float4*)&lds[wv][512 + 8*l]     = make_float4(cs[8], cs[9], cs[10], cs[11]);
    *(float4*)&lds[wv][512 + 8*l + 4] = make_float4(cs[12], cs[13], cs[14], cs[15]);
    __syncthreads();
    const int j = t * 4;
    float4 p0 = *(const float4*)&lds[0][j];
    float4 p1 = *(const float4*)&lds[1][j];
    float4 p2 = *(const float4*)&lds[2][j];
    float4 p3 = *(const float4*)&lds[3][j];
    float4 o;
    o.x = p0.x + p1.x + p2.x + p3.x;  o.y = p0.y + p1.y + p2.y + p3.y;
    o.z = p0.z + p1.z + p2.z + p3.z;  o.w = p0.w + p1.w + p2.w + p3.w;
    *(float4*)(partial + ((size_t)s * 128 + slab) * N_ + j) = o;
}

// ===========================================================================
// reduce_V<NS>: V[s][j] = 1 / sum_slab partial[s][slab][j]. Compile-time trip
// count, fully unrolled -> NS independent loads in flight (round-9 lesson).
// ===========================================================================
template<int NS>
__global__ void __launch_bounds__(256)
reduce_V(const float* __restrict__ partial, float* __restrict__ V) {
    const int s = blockIdx.x >> 2;
    const int j = (blockIdx.x & 3) * 256 + threadIdx.x;
    const float* p = partial + (size_t)s * NS * N_ + j;
    float acc = 0.f;
    #pragma unroll
    for (int q = 0; q < NS; ++q) acc += p[(size_t)q * N_];
    V[s * N_ + j] = 1.0f / acc;
}

// ===========================================================================
// sink_iter (round-5 proven body + do_colsum flag): fused row pass +
// next col-pass partials. 1024 blocks, 16 rows/block, 4 rows/wave.
//   U_i = 1 / sum_j K[i][j] V_j ;  partial[s][slab][j] = sum_i K[i][j] U_i
// ===========================================================================
__global__ void __launch_bounds__(256)
sink_iter(const unsigned short* __restrict__ Kb, const float* __restrict__ V,
          float* __restrict__ U, float* __restrict__ partial, int do_colsum) {
    const int bid = blockIdx.x;
    const int s    = (bid & 7) + 8 * ((bid >> 3) & 1);
    const int slab = bid >> 4;                 // 0..63
    const int t = threadIdx.x, wv = t >> 6, l = t & 63;

    // lane-owned columns: 8l..8l+7 and 512+8l..512+8l+7
    float v[16];
    const float* Vp = V + s * N_;
    *(float4*)&v[0]  = *(const float4*)(Vp + 8*l);
    *(float4*)&v[4]  = *(const float4*)(Vp + 8*l + 4);
    *(float4*)&v[8]  = *(const float4*)(Vp + 512 + 8*l);
    *(float4*)&v[12] = *(const float4*)(Vp + 512 + 8*l + 4);

    float cs[16];
    #pragma unroll
    for (int e = 0; e < 16; ++e) cs[e] = 0.f;

    const int i0 = slab * 16 + wv * 4;
    const unsigned short* rowp = Kb + ((size_t)s * N_ + i0) * N_;
    #pragma unroll
    for (int rr = 0; rr < 4; ++rr, rowp += N_) {
        uint4 ra = *(const uint4*)(rowp + 8*l);
        uint4 rb = *(const uint4*)(rowp + 512 + 8*l);
        float kf[16];
        unpack16(ra, rb, kf);
        float dot = 0.f;
        #pragma unroll
        for (int e = 0; e < 16; ++e) dot += kf[e] * v[e];
        #pragma unroll
        for (int m = 32; m >= 1; m >>= 1) dot += __shfl_xor(dot, m);
        const float ui = 1.0f / dot;
        if (l == 0) U[s * N_ + i0 + rr] = ui;
        #pragma unroll
        for (int e = 0; e < 16; ++e) cs[e] += kf[e] * ui;
    }

    if (!do_colsum) return;
    __shared__ float lds[4][1024];
    *(float4*)&lds[wv][8*l]           = make_float4(cs[0], cs[1], cs[2], cs[3]);
    *(float4*)&lds[wv][8*l + 4]       = make_float4(cs[4], cs[5], cs[6], cs[7]);
    *(float4*)&lds[wv][512 + 8*l]     = make_float4(cs[8], cs[9], cs[10], cs[11]);
    *(float4*)&lds[wv][512 + 8*l + 4] = make_float4(cs[12], cs[13], cs[14], cs[15]);
    __syncthreads();
    const int j = t * 4;
    float4 p0 = *(const float4*)&lds[0][j];
    float4 p1 = *(const float4*)&lds[1][j];
    float4 p2 = *(const float4*)&lds[2][j];
    float4 p3 = *(const float4*)&lds[3][j];
    float4 o;
    o.x = p0.x + p1.x + p2.x + p3.x;  o.y = p0.y + p1.y + p2.y + p3.y;
    o.z = p0.z + p1.z + p2.z + p3.z;  o.w = p0.w + p1.w + p2.w + p3.w;
    *(float4*)(partial + ((size_t)s * 64 + slab) * N_ + j) = o;
}

// ===========================================================================
// transpose_K: KbT[s][m][k] = Kb[s][k][m]  (after the loop; the partial
// buffer aliases the front of KbT and is dead by then).
// ===========================================================================
__global__ void __launch_bounds__(256)
transpose_K(const unsigned short* __restrict__ Kb, unsigned short* __restrict__ KbT) {
    const int s = blockIdx.z, k0 = blockIdx.x * 64, m0 = blockIdx.y * 64;
    __shared__ unsigned short tile[64][66];
    const int t = threadIdx.x, c4 = (t & 15) * 4, rr = t >> 4;
    const unsigned short* src = Kb + (size_t)s * N_ * N_;
    unsigned short* dst = KbT + (size_t)s * N_ * N_;
    #pragma unroll
    for (int q = 0; q < 4; ++q) {
        const int r = q * 16 + rr;
        ushort4 v = *(const ushort4*)(src + (size_t)(k0 + r) * N_ + m0 + c4);
        tile[r][c4] = v.x; tile[r][c4 + 1] = v.y; tile[r][c4 + 2] = v.z; tile[r][c4 + 3] = v.w;
    }
    __syncthreads();
    #pragma unroll
    for (int q = 0; q < 4; ++q) {
        const int rm = q * 16 + rr;
        ushort4 v;
        v.x = tile[c4][rm]; v.y = tile[c4 + 1][rm];
        v.z = tile[c4 + 2][rm]; v.w = tile[c4 + 3][rm];
        *(ushort4*)(dst + (size_t)(m0 + rm) * N_ + k0 + c4) = v;
    }
}

// ===========================================================================
// mfma_out (EXACT round-5 version, measured inside the 272us total):
// out[s][b][m] = V_m * sum_k (x[b][k]U_k) K[k][m], bf16 MFMA 16x16x32.
// 256 threads, 4 waves, wave tile 64(b) x 32(m) = 4x2 fragments.
// BM=128 BN=64 BK=64, XOR-swizzled LDS, register prefetch.
// ===========================================================================
__global__ void __launch_bounds__(256)
mfma_out(const float* __restrict__ x, const unsigned short* __restrict__ KbT,
         const float* __restrict__ U, const float* __restrict__ V,
         float* __restrict__ out) {
    const int s  = blockIdx.z;
    const int m0 = blockIdx.x * 64;
    const int b0 = blockIdx.y * 128;
    const int t  = threadIdx.x;
    const int wid = t >> 6, l = t & 63;
    const int wr = wid >> 1, wc = wid & 1;

    __shared__ alignas(16) unsigned short lsA[128 * 64];
    __shared__ alignas(16) unsigned short lsB[64 * 64];

    f32x4 acc[4][2];
    #pragma unroll
    for (int fi = 0; fi < 4; ++fi)
        #pragma unroll
        for (int fj = 0; fj < 2; ++fj)
            acc[fi][fj] = (f32x4){0.f, 0.f, 0.f, 0.f};

    const unsigned short* Bp = KbT + ((size_t)s * N_ + m0) * N_;
    const float* Up = U + s * N_;

    float4 xa[4], xb[4];
    uint4  kv[2];
    float4 ua[2], ub[2];

    auto load_tile = [&](int k0) {
        #pragma unroll
        for (int i = 0; i < 4; ++i) {
            const int Lb  = i * 4096 + t * 16;
            const int row = Lb >> 7;
            const int kb  = Lb & 127;
            const float* xp = x + (size_t)(b0 + row) * N_ + k0 + (kb >> 1);
            xa[i] = *(const float4*)xp;
            xb[i] = *(const float4*)(xp + 4);
        }
        #pragma unroll
        for (int i = 0; i < 2; ++i) {
            const int Lb  = i * 4096 + t * 16;
            const int row = Lb >> 7;
            const int kb  = Lb & 127;
            kv[i] = *(const uint4*)((const char*)Bp + (size_t)row * 2048 + (k0 << 1) + kb);
            const int ke = k0 + (kb >> 1);
            ua[i] = *(const float4*)(Up + ke);
            ub[i] = *(const float4*)(Up + ke + 4);
        }
    };

    load_tile(0);
    for (int k0 = 0; k0 < N_; k0 += 64) {
        __syncthreads();
        #pragma unroll
        for (int i = 0; i < 4; ++i) {
            const int Lb  = i * 4096 + t * 16;
            const int row = Lb >> 7;
            const int kb  = Lb & 127;
            uint4 pk = make_uint4(pack2(xa[i].x, xa[i].y), pack2(xa[i].z, xa[i].w),
                                  pack2(xb[i].x, xb[i].y), pack2(xb[i].z, xb[i].w));
            *(uint4*)((char*)lsA + (row << 7) + (kb ^ ((row & 7) << 4))) = pk;
        }
        #pragma unroll
        for (int i = 0; i < 2; ++i) {
            const int Lb  = i * 4096 + t * 16;
            const int row = Lb >> 7;
            const int kb  = Lb & 127;
            uint4 pk;
            pk.x = pack2(bf2f((unsigned short)(kv[i].x & 0xffffu)) * ua[i].x,
                         bf2f((unsigned short)(kv[i].x >> 16))     * ua[i].y);
            pk.y = pack2(bf2f((unsigned short)(kv[i].y & 0xffffu)) * ua[i].z,
                         bf2f((unsigned short)(kv[i].y >> 16))     * ua[i].w);
            pk.z = pack2(bf2f((unsigned short)(kv[i].z & 0xffffu)) * ub[i].x,
                         bf2f((unsigned short)(kv[i].z >> 16))     * ub[i].y);
            pk.w = pack2(bf2f((unsigned short)(kv[i].w & 0xffffu)) * ub[i].z,
                         bf2f((unsigned short)(kv[i].w >> 16))     * ub[i].w);
            *(uint4*)((char*)lsB + (row << 7) + (kb ^ ((row & 7) << 4))) = pk;
        }
        __syncthreads();
        if (k0 + 64 < N_) load_tile(k0 + 64);
        #pragma unroll
        for (int ks = 0; ks < 2; ++ks) {
            const int koff = ks * 64 + ((l >> 4) << 4);
            short8 afr[4], bfr[2];
            #pragma unroll
            for (int fi = 0; fi < 4; ++fi) {
                const int r = wr * 64 + fi * 16 + (l & 15);
                afr[fi] = *(const short8*)((const char*)lsA + (r << 7) + (koff ^ ((r & 7) << 4)));
            }
            #pragma unroll
            for (int fj = 0; fj < 2; ++fj) {
                const int r = wc * 32 + fj * 16 + (l & 15);
                bfr[fj] = *(const short8*)((const char*)lsB + (r << 7) + (koff ^ ((r & 7) << 4)));
            }
            #pragma unroll
            for (int fi = 0; fi < 4; ++fi)
                #pragma unroll
                for (int fj = 0; fj < 2; ++fj)
                    acc[fi][fj] = __builtin_amdgcn_mfma_f32_16x16x32_bf16(
                        afr[fi], bfr[fj], acc[fi][fj], 0, 0, 0);
        }
    }
    #pragma unroll
    for (int fj = 0; fj < 2; ++fj) {
        const int m = m0 + wc * 32 + fj * 16 + (l & 15);
        const float vm = V[s * N_ + m];
        #pragma unroll
        for (int fi = 0; fi < 4; ++fi) {
            const int b = b0 + wr * 64 + fi * 16 + ((l >> 4) << 2);
            float* op = out + ((size_t)s * B_ + b) * N_ + m;
            #pragma unroll
            for (int e = 0; e < 4; ++e)
                op[(size_t)e * N_] = acc[fi][fj][e] * vm;
        }
    }
}

// ===========================================================================
// FALLBACK PATH (round-1 proven kernels) — used only if ws is too small.
// ===========================================================================
__global__ void __launch_bounds__(256)
transpose_x(const float* __restrict__ x, float* __restrict__ xT) {
    __shared__ float tile[32][33];
    const int tx = threadIdx.x, ty = threadIdx.y;
    const int gx = blockIdx.x * 32, gy = blockIdx.y * 32;
    #pragma unroll
    for (int i = 0; i < 4; ++i)
        tile[ty + i * 8][tx] = x[(gy + ty + i * 8) * N_ + gx + tx];
    __syncthreads();
    #pragma unroll
    for (int i = 0; i < 4; ++i)
        xT[(size_t)(gx + ty + i * 8) * B_ + gy + tx] = tile[tx][ty + i * 8];
}

__global__ void __launch_bounds__(256)
col_pass(const float* __restrict__ u, const float* __restrict__ la,
         const float* __restrict__ r, float* __restrict__ c) {
    const int s = blockIdx.y, t = threadIdx.x;
    const int tx = t & 15, rg = t >> 4;
    const int j = blockIdx.x * 16 + tx;
    __shared__ alignas(16) float r_lds[N_];
    ((float4*)r_lds)[t] = ((const float4*)(r + s * N_))[t];
    __syncthreads();
    const float cj = c[s * N_ + j];
    const float* up = u + (size_t)s * N_ * N_;
    const int i0 = rg * 64;
    float acc = 0.f;
    #pragma unroll 4
    for (int ii = 0; ii < 64; ++ii) {
        const int i = i0 + ii;
        acc += __expf(la0_of(up[(size_t)i * N_ + j], la[i * N_ + j]) - r_lds[i] - cj);
    }
    __shared__ float sums[16][17];
    sums[rg][tx] = acc;
    __syncthreads();
    if (t < 16) {
        float tot = 0.f;
        #pragma unroll
        for (int k = 0; k < 16; ++k) tot += sums[k][t];
        c[s * N_ + blockIdx.x * 16 + t] = cj + __logf(tot);
    }
}

__global__ void __launch_bounds__(256)
row_pass(const float* __restrict__ u, const float* __restrict__ la,
         const float* __restrict__ c, float* __restrict__ r) {
    const int s = blockIdx.y, t = threadIdx.x;
    const int w = t >> 6, l = t & 63;
    const int i = blockIdx.x * 4 + w;
    __shared__ alignas(16) float c_lds[N_];
    ((float4*)c_lds)[t] = ((const float4*)(c + s * N_))[t];
    __syncthreads();
    const float ri = r[s * N_ + i];
    const float* up = u + (size_t)s * N_ * N_ + (size_t)i * N_;
    const float* lap = la + (size_t)i * N_;
    float acc = 0.f;
    #pragma unroll
    for (int k = 0; k < 16; ++k) {
        const int jj = l + (k << 6);
        acc += __expf(la0_of(up[jj], lap[jj]) - c_lds[jj] - ri);
    }
    #pragma unroll
    for (int m = 32; m >= 1; m >>= 1) acc += __shfl_xor(acc, m);
    if (l == 0) r[s * N_ + i] = ri + __logf(acc);
}

__global__ void __launch_bounds__(256)
matmul_out(const float* __restrict__ u, const float* __restrict__ la,
           const float* __restrict__ xT, const float* __restrict__ r,
           const float* __restrict__ c, float* __restrict__ out) {
    const int s = blockIdx.z, m0 = blockIdx.x * 64, b0 = blockIdx.y * 128;
    const int t = threadIdx.x, tx = t & 7, ty = t >> 3;
    __shared__ alignas(16) float Bs[16][64];
    float acc[4][8] = {};
    const float* up = u + (size_t)s * N_ * N_;
    const float* rp = r + s * N_;
    for (int k0 = 0; k0 < N_; k0 += 16) {
        __syncthreads();
        {
            const int kk = t >> 4, f4 = t & 15;
            const int k = k0 + kk;
            const float rk = rp[k];
            const float4 uv = *(const float4*)(up + (size_t)k * N_ + m0 + f4 * 4);
            const float4 lv = *(const float4*)(la + (size_t)k * N_ + m0 + f4 * 4);
            float4 p;
            p.x = __expf(la0_of(uv.x, lv.x) - rk);
            p.y = __expf(la0_of(uv.y, lv.y) - rk);
            p.z = __expf(la0_of(uv.z, lv.z) - rk);
            p.w = __expf(la0_of(uv.w, lv.w) - rk);
            *(float4*)(&Bs[kk][f4 * 4]) = p;
        }
        __syncthreads();
        #pragma unroll
        for (int kk = 0; kk < 16; ++kk) {
            const float4 a4 = *(const float4*)(xT + (size_t)(k0 + kk) * B_ + b0 + ty * 4);
            const float4 bA = *(const float4*)(&Bs[kk][tx * 8]);
            const float4 bB = *(const float4*)(&Bs[kk][tx * 8 + 4]);
            const float av[4] = {a4.x, a4.y, a4.z, a4.w};
            const float bv[8] = {bA.x, bA.y, bA.z, bA.w, bB.x, bB.y, bB.z, bB.w};
            #pragma unroll
            for (int rr = 0; rr < 4; ++rr)
                #pragma unroll
                for (int cc = 0; cc < 8; ++cc)
                    acc[rr][cc] += av[rr] * bv[cc];
        }
    }
    float cm[8];
    #pragma unroll
    for (int cc = 0; cc < 8; ++cc) cm[cc] = __expf(-c[s * N_ + m0 + tx * 8 + cc]);
    #pragma unroll
    for (int rr = 0; rr < 4; ++rr) {
        float4 o0, o1;
        o0.x = acc[rr][0] * cm[0]; o0.y = acc[rr][1] * cm[1];
        o0.z = acc[rr][2] * cm[2]; o0.w = acc[rr][3] * cm[3];
        o1.x = acc[rr][4] * cm[4]; o1.y = acc[rr][5] * cm[5];
        o1.z = acc[rr][6] * cm[6]; o1.w = acc[rr][7] * cm[7];
        float* op = out + ((size_t)s * B_ + b0 + ty * 4 + rr) * N_ + m0 + tx * 8;
        *(float4*)op       = o0;
        *(float4*)(op + 4) = o1;
    }
}

// ===========================================================================
extern "C" void kernel_launch(void* const* d_in, const int* in_sizes, int n_in,
                              void* d_out, int out_size, void* d_ws, size_t ws_size,
                              hipStream_t stream) {
    (void)in_sizes; (void)n_in; (void)out_size;
    const float* x  = (const float*)d_in[0];   // (256, 1024)
    const float* la = (const float*)d_in[1];   // (1024, 1024)
    const float* u  = (const float*)d_in[2];   // (16, 1024, 1024)
    float* out = (float*)d_out;                // (16, 256, 1024) f32

    const size_t KN = (size_t)S_ * N_ * N_;
    const size_t need = KN * 2 * 2               // Kb + KbT (bf16)
                      + (size_t)2 * S_ * N_ * 4; // U, V

    if (ws_size >= need) {
        unsigned short* Kb  = (unsigned short*)d_ws;
        unsigned short* KbT = Kb + KN;
        float* partial = (float*)KbT;            // <=8MB alias, dead before transpose_K
        float* U = (float*)(KbT + KN);
        float* V = U + S_ * N_;

        // 1) build K (bf16) + seed col-pass partials with U=1 (128 slabs)
        build_K2<<<2048, 256, 0, stream>>>(u, la, Kb, partial);

        // 2) 21 Sinkhorn iterations: finalize V, then fused row+colsum pass
        for (int it = 0; it < ITERS; ++it) {
            if (it == 0) reduce_V<128><<<64, 256, 0, stream>>>(partial, V);
            else         reduce_V<64><<<64, 256, 0, stream>>>(partial, V);
            sink_iter<<<1024, 256, 0, stream>>>(Kb, V, U, partial,
                                                it == ITERS - 1 ? 0 : 1);
        }

        // 3) KbT for the matmul's B operand (partial is dead now)
        transpose_K<<<dim3(16, 16, 16), 256, 0, stream>>>(Kb, KbT);

        // 4) out = diag-scaled GEMM via bf16 MFMA (round-5 256-thread kernel)
        mfma_out<<<dim3(N_ / 64, B_ / 128, S_), 256, 0, stream>>>(x, KbT, U, V, out);
    } else {
        float* r  = (float*)d_ws;
        float* c  = r + S_ * N_;
        float* xT = c + S_ * N_;
        (void)hipMemsetAsync(d_ws, 0, 2 * S_ * N_ * sizeof(float), stream);
        transpose_x<<<dim3(N_ / 32, B_ / 32), dim3(32, 8), 0, stream>>>(x, xT);
        for (int it = 0; it < ITERS; ++it) {
            col_pass<<<dim3(N_ / 16, S_), 256, 0, stream>>>(u, la, r, c);
            row_pass<<<dim3(N_ / 4, S_),  256, 0, stream>>>(u, la, c, r);
        }
        matmul_out<<<dim3(N_ / 64, B_ / 128, S_), 256, 0, stream>>>(u, la, xT, r, c, out);
    }
}

// Round 14
// 275.562 us; speedup vs baseline: 3.6008x; 1.1065x over previous
//
#include <hip/hip_runtime.h>
#include <math.h>

// Problem constants (fixed by the reference: B=256, N=1024, S=16, 21 iters)
static constexpr int S_ = 16;
static constexpr int N_ = 1024;
static constexpr int B_ = 256;
static constexpr int ITERS = 21;
#define EPSC 1e-10f

using short8 = __attribute__((ext_vector_type(8))) short;
using f32x4  = __attribute__((ext_vector_type(4))) float;

// ---------------- bf16 helpers (raw ushort bits) ----------------
__device__ __forceinline__ float bf2f(unsigned short h) {
    union { unsigned int u; float f; } v; v.u = ((unsigned int)h) << 16; return v.f;
}
__device__ __forceinline__ unsigned short f2bf(float f) {
    union { float f; unsigned int u; } v; v.f = f;
    unsigned int r = v.u + 0x7fffu + ((v.u >> 16) & 1u);   // round-nearest-even
    return (unsigned short)(r >> 16);
}
__device__ __forceinline__ unsigned int pack2(float a, float b) {
    return (unsigned int)f2bf(a) | ((unsigned int)f2bf(b) << 16);
}

// la0 = log_alpha + gumbel_noise(u), noise = -log(EPS - log(u + EPS)).
__device__ __forceinline__ float la0_of(float uv, float lav) {
    float t1 = __logf(uv + EPSC);
    float t2 = EPSC - t1;
    return lav - __logf(t2);
}

__device__ __forceinline__ void unpack16(const uint4& a, const uint4& b, float* kf) {
    kf[0]  = bf2f((unsigned short)(a.x & 0xffffu)); kf[1]  = bf2f((unsigned short)(a.x >> 16));
    kf[2]  = bf2f((unsigned short)(a.y & 0xffffu)); kf[3]  = bf2f((unsigned short)(a.y >> 16));
    kf[4]  = bf2f((unsigned short)(a.z & 0xffffu)); kf[5]  = bf2f((unsigned short)(a.z >> 16));
    kf[6]  = bf2f((unsigned short)(a.w & 0xffffu)); kf[7]  = bf2f((unsigned short)(a.w >> 16));
    kf[8]  = bf2f((unsigned short)(b.x & 0xffffu)); kf[9]  = bf2f((unsigned short)(b.x >> 16));
    kf[10] = bf2f((unsigned short)(b.y & 0xffffu)); kf[11] = bf2f((unsigned short)(b.y >> 16));
    kf[12] = bf2f((unsigned short)(b.z & 0xffffu)); kf[13] = bf2f((unsigned short)(b.z >> 16));
    kf[14] = bf2f((unsigned short)(b.w & 0xffffu)); kf[15] = bf2f((unsigned short)(b.w >> 16));
}

// Block mapping for the 1024-block kernels: xcd = bid&7 (HW round-robin),
// sample s = xcd + 8*((bid>>3)&1), slab = bid>>4 (0..63, 16 rows each).
#define MAP_S_SLAB(bid, s, slab) \
    const int s = ((bid) & 7) + 8 * (((bid) >> 3) & 1); \
    const int slab = (bid) >> 4;

// ===========================================================================
// build_K2 (EXACT round-5 version, measured 43.7us inside the 272us total):
// K[s][i][j] = exp(la)/(EPS - log(u+EPS)) bf16 (write Kb) + seed col-pass
// partials with U=1: partial[s][slab][j] = sum_i K[i][j]. 1024 blocks,
// 16 rows/block, 4 rows/wave, plain loads (round-13 lesson: the 2048-block
// "batched NT load" variant regressed ~30us — VGPR=32 shows the compiler
// serialized the batch, and NT bypassed L2/L3 caching of u).
// ===========================================================================
__global__ void __launch_bounds__(256)
build_K2(const float* __restrict__ u, const float* __restrict__ la,
         unsigned short* __restrict__ Kb, float* __restrict__ partial) {
    MAP_S_SLAB(blockIdx.x, s, slab)
    const int t = threadIdx.x, wv = t >> 6, l = t & 63;
    float cs[16];
    #pragma unroll
    for (int e = 0; e < 16; ++e) cs[e] = 0.f;

    const int i0 = slab * 16 + wv * 4;
    #pragma unroll
    for (int rr = 0; rr < 4; ++rr) {
        const int i = i0 + rr;
        const float* up  = u  + ((size_t)s * N_ + i) * N_;
        const float* lap = la + (size_t)i * N_;
        float kf[16];
        #pragma unroll
        for (int h = 0; h < 2; ++h) {        // column halves: 8l, 512+8l
            const int c = h * 512 + 8 * l;
            float4 ua = *(const float4*)(up + c);
            float4 ub = *(const float4*)(up + c + 4);
            float4 la4 = *(const float4*)(lap + c);
            float4 lb4 = *(const float4*)(lap + c + 4);
            const float uf[8] = {ua.x, ua.y, ua.z, ua.w, ub.x, ub.y, ub.z, ub.w};
            const float lf[8] = {la4.x, la4.y, la4.z, la4.w, lb4.x, lb4.y, lb4.z, lb4.w};
            unsigned int pk[4];
            #pragma unroll
            for (int e = 0; e < 4; ++e) {
                float k0 = __expf(lf[2*e])   / (EPSC - __logf(uf[2*e]   + EPSC));
                float k1 = __expf(lf[2*e+1]) / (EPSC - __logf(uf[2*e+1] + EPSC));
                unsigned short b0 = f2bf(k0), b1 = f2bf(k1);
                pk[e] = (unsigned int)b0 | ((unsigned int)b1 << 16);
                kf[h*8 + 2*e]     = bf2f(b0);
                kf[h*8 + 2*e + 1] = bf2f(b1);
            }
            *(uint4*)(Kb + ((size_t)s * N_ + i) * N_ + c) =
                make_uint4(pk[0], pk[1], pk[2], pk[3]);
        }
        #pragma unroll
        for (int e = 0; e < 16; ++e) cs[e] += kf[e];
    }

    // combine 4 waves' partial colsums, write partial[s][slab][:] (64 slabs)
    __shared__ float lds[4][1024];
    *(float4*)&lds[wv][8*l]           = make_float4(cs[0], cs[1], cs[2], cs[3]);
    *(float4*)&lds[wv][8*l + 4]       = make_float4(cs[4], cs[5], cs[6], cs[7]);
    *(float4*)&lds[wv][512 + 8*l]     = make_float4(cs[8], cs[9], cs[10], cs[11]);
    *(float4*)&lds[wv][512 + 8*l + 4] = make_float4(cs[12], cs[13], cs[14], cs[15]);
    __syncthreads();
    const int j = t * 4;
    float4 p0 = *(const float4*)&lds[0][j];
    float4 p1 = *(const float4*)&lds[1][j];
    float4 p2 = *(const float4*)&lds[2][j];
    float4 p3 = *(const float4*)&lds[3][j];
    float4 o;
    o.x = p0.x + p1.x + p2.x + p3.x;  o.y = p0.y + p1.y + p2.y + p3.y;
    o.z = p0.z + p1.z + p2.z + p3.z;  o.w = p0.w + p1.w + p2.w + p3.w;
    *(float4*)(partial + ((size_t)s * 64 + slab) * N_ + j) = o;
}

// ===========================================================================
// reduce_V<NS>: V[s][j] = 1 / sum_slab partial[s][slab][j]. Compile-time trip
// count, fully unrolled -> NS independent loads in flight (round-9 lesson).
// ===========================================================================
template<int NS>
__global__ void __launch_bounds__(256)
reduce_V(const float* __restrict__ partial, float* __restrict__ V) {
    const int s = blockIdx.x >> 2;
    const int j = (blockIdx.x & 3) * 256 + threadIdx.x;
    const float* p = partial + (size_t)s * NS * N_ + j;
    float acc = 0.f;
    #pragma unroll
    for (int q = 0; q < NS; ++q) acc += p[(size_t)q * N_];
    V[s * N_ + j] = 1.0f / acc;
}

// ===========================================================================
// sink_iter (round-5 proven body + do_colsum flag): fused row pass +
// next col-pass partials. 1024 blocks, 16 rows/block, 4 rows/wave.
//   U_i = 1 / sum_j K[i][j] V_j ;  partial[s][slab][j] = sum_i K[i][j] U_i
// ===========================================================================
__global__ void __launch_bounds__(256)
sink_iter(const unsigned short* __restrict__ Kb, const float* __restrict__ V,
          float* __restrict__ U, float* __restrict__ partial, int do_colsum) {
    MAP_S_SLAB(blockIdx.x, s, slab)
    const int t = threadIdx.x, wv = t >> 6, l = t & 63;

    // lane-owned columns: 8l..8l+7 and 512+8l..512+8l+7
    float v[16];
    const float* Vp = V + s * N_;
    *(float4*)&v[0]  = *(const float4*)(Vp + 8*l);
    *(float4*)&v[4]  = *(const float4*)(Vp + 8*l + 4);
    *(float4*)&v[8]  = *(const float4*)(Vp + 512 + 8*l);
    *(float4*)&v[12] = *(const float4*)(Vp + 512 + 8*l + 4);

    float cs[16];
    #pragma unroll
    for (int e = 0; e < 16; ++e) cs[e] = 0.f;

    const int i0 = slab * 16 + wv * 4;
    const unsigned short* rowp = Kb + ((size_t)s * N_ + i0) * N_;
    #pragma unroll
    for (int rr = 0; rr < 4; ++rr, rowp += N_) {
        uint4 ra = *(const uint4*)(rowp + 8*l);
        uint4 rb = *(const uint4*)(rowp + 512 + 8*l);
        float kf[16];
        unpack16(ra, rb, kf);
        float dot = 0.f;
        #pragma unroll
        for (int e = 0; e < 16; ++e) dot += kf[e] * v[e];
        #pragma unroll
        for (int m = 32; m >= 1; m >>= 1) dot += __shfl_xor(dot, m);
        const float ui = 1.0f / dot;
        if (l == 0) U[s * N_ + i0 + rr] = ui;
        #pragma unroll
        for (int e = 0; e < 16; ++e) cs[e] += kf[e] * ui;
    }

    if (!do_colsum) return;
    __shared__ float lds[4][1024];
    *(float4*)&lds[wv][8*l]           = make_float4(cs[0], cs[1], cs[2], cs[3]);
    *(float4*)&lds[wv][8*l + 4]       = make_float4(cs[4], cs[5], cs[6], cs[7]);
    *(float4*)&lds[wv][512 + 8*l]     = make_float4(cs[8], cs[9], cs[10], cs[11]);
    *(float4*)&lds[wv][512 + 8*l + 4] = make_float4(cs[12], cs[13], cs[14], cs[15]);
    __syncthreads();
    const int j = t * 4;
    float4 p0 = *(const float4*)&lds[0][j];
    float4 p1 = *(const float4*)&lds[1][j];
    float4 p2 = *(const float4*)&lds[2][j];
    float4 p3 = *(const float4*)&lds[3][j];
    float4 o;
    o.x = p0.x + p1.x + p2.x + p3.x;  o.y = p0.y + p1.y + p2.y + p3.y;
    o.z = p0.z + p1.z + p2.z + p3.z;  o.w = p0.w + p1.w + p2.w + p3.w;
    *(float4*)(partial + ((size_t)s * 64 + slab) * N_ + j) = o;
}

// ===========================================================================
// transpose_K: KbT[s][m][k] = Kb[s][k][m]  (after the loop; the partial
// buffer aliases the front of KbT and is dead by then).
// ===========================================================================
__global__ void __launch_bounds__(256)
transpose_K(const unsigned short* __restrict__ Kb, unsigned short* __restrict__ KbT) {
    const int s = blockIdx.z, k0 = blockIdx.x * 64, m0 = blockIdx.y * 64;
    __shared__ unsigned short tile[64][66];
    const int t = threadIdx.x, c4 = (t & 15) * 4, rr = t >> 4;
    const unsigned short* src = Kb + (size_t)s * N_ * N_;
    unsigned short* dst = KbT + (size_t)s * N_ * N_;
    #pragma unroll
    for (int q = 0; q < 4; ++q) {
        const int r = q * 16 + rr;
        ushort4 v = *(const ushort4*)(src + (size_t)(k0 + r) * N_ + m0 + c4);
        tile[r][c4] = v.x; tile[r][c4 + 1] = v.y; tile[r][c4 + 2] = v.z; tile[r][c4 + 3] = v.w;
    }
    __syncthreads();
    #pragma unroll
    for (int q = 0; q < 4; ++q) {
        const int rm = q * 16 + rr;
        ushort4 v;
        v.x = tile[c4][rm]; v.y = tile[c4 + 1][rm];
        v.z = tile[c4 + 2][rm]; v.w = tile[c4 + 3][rm];
        *(ushort4*)(dst + (size_t)(m0 + rm) * N_ + k0 + c4) = v;
    }
}

// ===========================================================================
// mfma_out (EXACT round-5 version): out[s][b][m] = V_m sum_k (x[b][k]U_k)K[k][m]
// bf16 MFMA 16x16x32. 256 threads, 4 waves, wave tile 64(b) x 32(m).
// BM=128 BN=64 BK=64, XOR-swizzled LDS, register prefetch.
// ===========================================================================
__global__ void __launch_bounds__(256)
mfma_out(const float* __restrict__ x, const unsigned short* __restrict__ KbT,
         const float* __restrict__ U, const float* __restrict__ V,
         float* __restrict__ out) {
    const int s  = blockIdx.z;
    const int m0 = blockIdx.x * 64;
    const int b0 = blockIdx.y * 128;
    const int t  = threadIdx.x;
    const int wid = t >> 6, l = t & 63;
    const int wr = wid >> 1, wc = wid & 1;

    __shared__ alignas(16) unsigned short lsA[128 * 64];
    __shared__ alignas(16) unsigned short lsB[64 * 64];

    f32x4 acc[4][2];
    #pragma unroll
    for (int fi = 0; fi < 4; ++fi)
        #pragma unroll
        for (int fj = 0; fj < 2; ++fj)
            acc[fi][fj] = (f32x4){0.f, 0.f, 0.f, 0.f};

    const unsigned short* Bp = KbT + ((size_t)s * N_ + m0) * N_;
    const float* Up = U + s * N_;

    float4 xa[4], xb[4];
    uint4  kv[2];
    float4 ua[2], ub[2];

    auto load_tile = [&](int k0) {
        #pragma unroll
        for (int i = 0; i < 4; ++i) {
            const int Lb  = i * 4096 + t * 16;
            const int row = Lb >> 7;
            const int kb  = Lb & 127;
            const float* xp = x + (size_t)(b0 + row) * N_ + k0 + (kb >> 1);
            xa[i] = *(const float4*)xp;
            xb[i] = *(const float4*)(xp + 4);
        }
        #pragma unroll
        for (int i = 0; i < 2; ++i) {
            const int Lb  = i * 4096 + t * 16;
            const int row = Lb >> 7;
            const int kb  = Lb & 127;
            kv[i] = *(const uint4*)((const char*)Bp + (size_t)row * 2048 + (k0 << 1) + kb);
            const int ke = k0 + (kb >> 1);
            ua[i] = *(const float4*)(Up + ke);
            ub[i] = *(const float4*)(Up + ke + 4);
        }
    };

    load_tile(0);
    for (int k0 = 0; k0 < N_; k0 += 64) {
        __syncthreads();
        #pragma unroll
        for (int i = 0; i < 4; ++i) {
            const int Lb  = i * 4096 + t * 16;
            const int row = Lb >> 7;
            const int kb  = Lb & 127;
            uint4 pk = make_uint4(pack2(xa[i].x, xa[i].y), pack2(xa[i].z, xa[i].w),
                                  pack2(xb[i].x, xb[i].y), pack2(xb[i].z, xb[i].w));
            *(uint4*)((char*)lsA + (row << 7) + (kb ^ ((row & 7) << 4))) = pk;
        }
        #pragma unroll
        for (int i = 0; i < 2; ++i) {
            const int Lb  = i * 4096 + t * 16;
            const int row = Lb >> 7;
            const int kb  = Lb & 127;
            uint4 pk;
            pk.x = pack2(bf2f((unsigned short)(kv[i].x & 0xffffu)) * ua[i].x,
                         bf2f((unsigned short)(kv[i].x >> 16))     * ua[i].y);
            pk.y = pack2(bf2f((unsigned short)(kv[i].y & 0xffffu)) * ua[i].z,
                         bf2f((unsigned short)(kv[i].y >> 16))     * ua[i].w);
            pk.z = pack2(bf2f((unsigned short)(kv[i].z & 0xffffu)) * ub[i].x,
                         bf2f((unsigned short)(kv[i].z >> 16))     * ub[i].y);
            pk.w = pack2(bf2f((unsigned short)(kv[i].w & 0xffffu)) * ub[i].z,
                         bf2f((unsigned short)(kv[i].w >> 16))     * ub[i].w);
            *(uint4*)((char*)lsB + (row << 7) + (kb ^ ((row & 7) << 4))) = pk;
        }
        __syncthreads();
        if (k0 + 64 < N_) load_tile(k0 + 64);
        #pragma unroll
        for (int ks = 0; ks < 2; ++ks) {
            const int koff = ks * 64 + ((l >> 4) << 4);
            short8 afr[4], bfr[2];
            #pragma unroll
            for (int fi = 0; fi < 4; ++fi) {
                const int r = wr * 64 + fi * 16 + (l & 15);
                afr[fi] = *(const short8*)((const char*)lsA + (r << 7) + (koff ^ ((r & 7) << 4)));
            }
            #pragma unroll
            for (int fj = 0; fj < 2; ++fj) {
                const int r = wc * 32 + fj * 16 + (l & 15);
                bfr[fj] = *(const short8*)((const char*)lsB + (r << 7) + (koff ^ ((r & 7) << 4)));
            }
            #pragma unroll
            for (int fi = 0; fi < 4; ++fi)
                #pragma unroll
                for (int fj = 0; fj < 2; ++fj)
                    acc[fi][fj] = __builtin_amdgcn_mfma_f32_16x16x32_bf16(
                        afr[fi], bfr[fj], acc[fi][fj], 0, 0, 0);
        }
    }
    #pragma unroll
    for (int fj = 0; fj < 2; ++fj) {
        const int m = m0 + wc * 32 + fj * 16 + (l & 15);
        const float vm = V[s * N_ + m];
        #pragma unroll
        for (int fi = 0; fi < 4; ++fi) {
            const int b = b0 + wr * 64 + fi * 16 + ((l >> 4) << 2);
            float* op = out + ((size_t)s * B_ + b) * N_ + m;
            #pragma unroll
            for (int e = 0; e < 4; ++e)
                op[(size_t)e * N_] = acc[fi][fj][e] * vm;
        }
    }
}

// ===========================================================================
// FALLBACK PATH (round-1 proven kernels) — used only if ws is too small.
// ===========================================================================
__global__ void __launch_bounds__(256)
transpose_x(const float* __restrict__ x, float* __restrict__ xT) {
    __shared__ float tile[32][33];
    const int tx = threadIdx.x, ty = threadIdx.y;
    const int gx = blockIdx.x * 32, gy = blockIdx.y * 32;
    #pragma unroll
    for (int i = 0; i < 4; ++i)
        tile[ty + i * 8][tx] = x[(gy + ty + i * 8) * N_ + gx + tx];
    __syncthreads();
    #pragma unroll
    for (int i = 0; i < 4; ++i)
        xT[(size_t)(gx + ty + i * 8) * B_ + gy + tx] = tile[tx][ty + i * 8];
}

__global__ void __launch_bounds__(256)
col_pass(const float* __restrict__ u, const float* __restrict__ la,
         const float* __restrict__ r, float* __restrict__ c) {
    const int s = blockIdx.y, t = threadIdx.x;
    const int tx = t & 15, rg = t >> 4;
    const int j = blockIdx.x * 16 + tx;
    __shared__ alignas(16) float r_lds[N_];
    ((float4*)r_lds)[t] = ((const float4*)(r + s * N_))[t];
    __syncthreads();
    const float cj = c[s * N_ + j];
    const float* up = u + (size_t)s * N_ * N_;
    const int i0 = rg * 64;
    float acc = 0.f;
    #pragma unroll 4
    for (int ii = 0; ii < 64; ++ii) {
        const int i = i0 + ii;
        acc += __expf(la0_of(up[(size_t)i * N_ + j], la[i * N_ + j]) - r_lds[i] - cj);
    }
    __shared__ float sums[16][17];
    sums[rg][tx] = acc;
    __syncthreads();
    if (t < 16) {
        float tot = 0.f;
        #pragma unroll
        for (int k = 0; k < 16; ++k) tot += sums[k][t];
        c[s * N_ + blockIdx.x * 16 + t] = cj + __logf(tot);
    }
}

__global__ void __launch_bounds__(256)
row_pass(const float* __restrict__ u, const float* __restrict__ la,
         const float* __restrict__ c, float* __restrict__ r) {
    const int s = blockIdx.y, t = threadIdx.x;
    const int w = t >> 6, l = t & 63;
    const int i = blockIdx.x * 4 + w;
    __shared__ alignas(16) float c_lds[N_];
    ((float4*)c_lds)[t] = ((const float4*)(c + s * N_))[t];
    __syncthreads();
    const float ri = r[s * N_ + i];
    const float* up = u + (size_t)s * N_ * N_ + (size_t)i * N_;
    const float* lap = la + (size_t)i * N_;
    float acc = 0.f;
    #pragma unroll
    for (int k = 0; k < 16; ++k) {
        const int jj = l + (k << 6);
        acc += __expf(la0_of(up[jj], lap[jj]) - c_lds[jj] - ri);
    }
    #pragma unroll
    for (int m = 32; m >= 1; m >>= 1) acc += __shfl_xor(acc, m);
    if (l == 0) r[s * N_ + i] = ri + __logf(acc);
}

__global__ void __launch_bounds__(256)
matmul_out(const float* __restrict__ u, const float* __restrict__ la,
           const float* __restrict__ xT, const float* __restrict__ r,
           const float* __restrict__ c, float* __restrict__ out) {
    const int s = blockIdx.z, m0 = blockIdx.x * 64, b0 = blockIdx.y * 128;
    const int t = threadIdx.x, tx = t & 7, ty = t >> 3;
    __shared__ alignas(16) float Bs[16][64];
    float acc[4][8] = {};
    const float* up = u + (size_t)s * N_ * N_;
    const float* rp = r + s * N_;
    for (int k0 = 0; k0 < N_; k0 += 16) {
        __syncthreads();
        {
            const int kk = t >> 4, f4 = t & 15;
            const int k = k0 + kk;
            const float rk = rp[k];
            const float4 uv = *(const float4*)(up + (size_t)k * N_ + m0 + f4 * 4);
            const float4 lv = *(const float4*)(la + (size_t)k * N_ + m0 + f4 * 4);
            float4 p;
            p.x = __expf(la0_of(uv.x, lv.x) - rk);
            p.y = __expf(la0_of(uv.y, lv.y) - rk);
            p.z = __expf(la0_of(uv.z, lv.z) - rk);
            p.w = __expf(la0_of(uv.w, lv.w) - rk);
            *(float4*)(&Bs[kk][f4 * 4]) = p;
        }
        __syncthreads();
        #pragma unroll
        for (int kk = 0; kk < 16; ++kk) {
            const float4 a4 = *(const float4*)(xT + (size_t)(k0 + kk) * B_ + b0 + ty * 4);
            const float4 bA = *(const float4*)(&Bs[kk][tx * 8]);
            const float4 bB = *(const float4*)(&Bs[kk][tx * 8 + 4]);
            const float av[4] = {a4.x, a4.y, a4.z, a4.w};
            const float bv[8] = {bA.x, bA.y, bA.z, bA.w, bB.x, bB.y, bB.z, bB.w};
            #pragma unroll
            for (int rr = 0; rr < 4; ++rr)
                #pragma unroll
                for (int cc = 0; cc < 8; ++cc)
                    acc[rr][cc] += av[rr] * bv[cc];
        }
    }
    float cm[8];
    #pragma unroll
    for (int cc = 0; cc < 8; ++cc) cm[cc] = __expf(-c[s * N_ + m0 + tx * 8 + cc]);
    #pragma unroll
    for (int rr = 0; rr < 4; ++rr) {
        float4 o0, o1;
        o0.x = acc[rr][0] * cm[0]; o0.y = acc[rr][1] * cm[1];
        o0.z = acc[rr][2] * cm[2]; o0.w = acc[rr][3] * cm[3];
        o1.x = acc[rr][4] * cm[4]; o1.y = acc[rr][5] * cm[5];
        o1.z = acc[rr][6] * cm[6]; o1.w = acc[rr][7] * cm[7];
        float* op = out + ((size_t)s * B_ + b0 + ty * 4 + rr) * N_ + m0 + tx * 8;
        *(float4*)op       = o0;
        *(float4*)(op + 4) = o1;
    }
}

// ===========================================================================
extern "C" void kernel_launch(void* const* d_in, const int* in_sizes, int n_in,
                              void* d_out, int out_size, void* d_ws, size_t ws_size,
                              hipStream_t stream) {
    (void)in_sizes; (void)n_in; (void)out_size;
    const float* x  = (const float*)d_in[0];   // (256, 1024)
    const float* la = (const float*)d_in[1];   // (1024, 1024)
    const float* u  = (const float*)d_in[2];   // (16, 1024, 1024)
    float* out = (float*)d_out;                // (16, 256, 1024) f32

    const size_t KN = (size_t)S_ * N_ * N_;
    const size_t need = KN * 2 * 2               // Kb + KbT (bf16)
                      + (size_t)2 * S_ * N_ * 4; // U, V

    if (ws_size >= need) {
        unsigned short* Kb  = (unsigned short*)d_ws;
        unsigned short* KbT = Kb + KN;
        float* partial = (float*)KbT;            // 4MB alias, dead before transpose_K
        float* U = (float*)(KbT + KN);
        float* V = U + S_ * N_;

        // 1) build K (bf16) + seed col-pass partials with U=1 (64 slabs)
        build_K2<<<1024, 256, 0, stream>>>(u, la, Kb, partial);

        // 2) 21 Sinkhorn iterations: finalize V, then fused row+colsum pass
        for (int it = 0; it < ITERS; ++it) {
            reduce_V<64><<<64, 256, 0, stream>>>(partial, V);
            sink_iter<<<1024, 256, 0, stream>>>(Kb, V, U, partial,
                                                it == ITERS - 1 ? 0 : 1);
        }

        // 3) KbT for the matmul's B operand (partial is dead now)
        transpose_K<<<dim3(16, 16, 16), 256, 0, stream>>>(Kb, KbT);

        // 4) out = diag-scaled GEMM via bf16 MFMA (round-5 256-thread kernel)
        mfma_out<<<dim3(N_ / 64, B_ / 128, S_), 256, 0, stream>>>(x, KbT, U, V, out);
    } else {
        float* r  = (float*)d_ws;
        float* c  = r + S_ * N_;
        float* xT = c + S_ * N_;
        (void)hipMemsetAsync(d_ws, 0, 2 * S_ * N_ * sizeof(float), stream);
        transpose_x<<<dim3(N_ / 32, B_ / 32), dim3(32, 8), 0, stream>>>(x, xT);
        for (int it = 0; it < ITERS; ++it) {
            col_pass<<<dim3(N_ / 16, S_), 256, 0, stream>>>(u, la, r, c);
            row_pass<<<dim3(N_ / 4, S_),  256, 0, stream>>>(u, la, c, r);
        }
        matmul_out<<<dim3(N_ / 64, B_ / 128, S_), 256, 0, stream>>>(u, la, xT, r, c, out);
    }
}